// Round 7
// baseline (170.600 us; speedup 1.0000x reference)
//
#include <hip/hip_runtime.h>

#define EMBD 264        // L1(256) + 8 psqt
#define NROWS 20481     // HALFKP+1
#define NR4   5121      // ceil(NROWS/4)
#define QS 5080.0f      // int8 scale: 127/0.025
#define INVQS (1.0f/5080.0f)

typedef short short8 __attribute__((ext_vector_type(8)));
typedef float f32x4  __attribute__((ext_vector_type(4)));

__device__ __forceinline__ float clamp01(float x) { return fminf(fmaxf(x, 0.f), 1.f); }
__device__ __forceinline__ unsigned short f2bf(float f) {
    unsigned u = __float_as_uint(f);
    u += 0x7fffu + ((u >> 16) & 1u);   // RNE
    return (unsigned short)(u >> 16);
}

// slot->feature permutation for the group-major A layout:
// stored A column c = g*8+e holds l0[ e<4 ? 4g+e : 128+4g+(e-4) ].
__device__ __forceinline__ int slot2feat(int c) {
    const int g = c >> 3, e = c & 7;
    return (e < 4) ? (g * 4 + e) : (128 + g * 4 + (e - 4));
}

// Merged prep.
// Blocks [0, NR4): quantize emb -> emb8 PAIRED row-major (r6 layout, verified):
//   dword t of row r = bytes [q(f_2t), q(f_{2t+128}), q(f_{2t+1}), q(f_{2t+129})]
// Blocks [NR4, NR4+256): w1b (bf16 MFMA B-frags, K-order PERMUTED to match the
//   group-major A layout), b1c, w2p.
// Blocks [NR4+256, NR4+768): pack w_idx/b_idx -> u16 ids16 (B,64): k<32 w, else b.
__global__ void prep_all(const float* __restrict__ emb, unsigned int* __restrict__ emb8,
                         float* __restrict__ psqt,
                         const float* __restrict__ w1, const float* __restrict__ fw1,
                         const float* __restrict__ b1, const float* __restrict__ fb1,
                         const float* __restrict__ w2,
                         const int* __restrict__ w_idx, const int* __restrict__ b_idx,
                         unsigned short* __restrict__ w1b, float* __restrict__ b1c,
                         float* __restrict__ w2p, unsigned* __restrict__ ids32) {
    if (blockIdx.x < NR4) {
        const int r = blockIdx.x * 4 + (threadIdx.x >> 6);
        const int t = threadIdx.x & 63;
        if (r >= NROWS) return;
        const bool pad = (r == NROWS - 1);
        const float2 va = *(const float2*)(emb + (size_t)r * EMBD + 2 * t);
        const float2 vb = *(const float2*)(emb + (size_t)r * EMBD + 128 + 2 * t);
        int q0 = pad ? 128 : (int)rintf(va.x * QS) + 128;   // f_{2t}
        int q1 = pad ? 128 : (int)rintf(vb.x * QS) + 128;   // f_{2t+128}
        int q2 = pad ? 128 : (int)rintf(va.y * QS) + 128;   // f_{2t+1}
        int q3 = pad ? 128 : (int)rintf(vb.y * QS) + 128;   // f_{2t+129}
        q0 = min(max(q0, 0), 255); q1 = min(max(q1, 0), 255);
        q2 = min(max(q2, 0), 255); q3 = min(max(q3, 0), 255);
        emb8[(size_t)r * 64 + t] = (unsigned)q0 | ((unsigned)q1 << 8) |
                                   ((unsigned)q2 << 16) | ((unsigned)q3 << 24);
        if (t < 8) {
            float pv = emb[(size_t)r * EMBD + 256 + t];
            psqt[r * 8 + t] = pad ? 0.f : pv;
        }
    } else if (blockIdx.x < NR4 + 256) {
        const int e = (blockIdx.x - NR4) * 256 + threadIdx.x;   // 0..65535
        const int bkt = e >> 13, rem = e & 8191;
        const int s = rem >> 10, rem2 = rem & 1023;
        const int nt = rem2 >> 9, rem3 = rem2 & 511;
        const int ln = rem3 >> 3, j = rem3 & 7;
        const int n  = nt * 16 + (ln & 15);
        const int hi = ln >> 4;
        const int kslot = s * 32 + hi * 8 + j;     // stored-A column
        const int k = slot2feat(kslot);            // actual l0 feature
        const float v = w1[(bkt * 32 + n) * 256 + k] + fw1[n * 256 + k];
        w1b[e] = f2bf(v);
        if (e < 256) b1c[e] = b1[e] + fb1[e & 31];
        if (e < 16384) {
            const int jr = e >> 6, i = e & 63;
            float x = 0.f;
            if (i < 31) x = w2[jr * 62 + i];
            else if (i >= 32 && i < 63) x = w2[jr * 62 + i - 1];
            w2p[e] = x;
        }
    } else {
        // ids16 pack: dword d covers refs (2k, 2k+1) of row d>>5.
        const int bi = blockIdx.x - (NR4 + 256);            // 0..511
        const int d0 = (bi * 256 + threadIdx.x) * 4;
#pragma unroll
        for (int u = 0; u < 4; ++u) {
            const int d = d0 + u;                           // < 524288
            const int row = d >> 5;
            const int kp = (d & 31) << 1;                   // even, 0..62
            const int a = (kp < 32) ? w_idx[row * 32 + kp]     : b_idx[row * 32 + kp - 32];
            const int b = (kp < 32) ? w_idx[row * 32 + kp + 1] : b_idx[row * 32 + kp - 31];
            ids32[d] = ((unsigned)a & 0xffffu) | ((unsigned)b << 16);
        }
    }
}

// ---------- phase 1 (LDS-resident table planes): gather + l0 ----------
// Rationale (r0-r6 post-mortems): every VMEM gather variant pinned at ~45us =
// ~3.1M random cache-line requests / (8 XCD x ~3 lines/cyc) -- a request-rate
// wall, not BW/latency/occupancy. Fix: take the random reads out of VMEM.
// The paired table = 32 column-planes of 8 B/row x 20480 rows = 160 KiB each
// = exactly one CU's LDS. Block (g,jb): loads plane g to LDS once, then
// lane-per-row streams its 2048-row batch slice: 64 serial LDS b64 reads/row
// (random LDS = ~2-way conflicts, ~free), integer-packed accumulate
// (bit-identical sums to the verified r6 math). Indices pre-packed u16 ->
// the 32x re-stream is 64 MB coalesced, L2-shared across co-XCD groups
// (bid=jb*32+g -> XCD=g%8: plane g L2-local, 4 groups/XCD share each slice).
// psqt (fp32 exact) stays VMEM: per-block 64-row duty chunk issued BEFORE the
// LDS fill so its random lines overlap the LDS compute of all blocks.
__global__ __launch_bounds__(1024) void g_phase1L(
    const unsigned int* __restrict__ emb8,    // (NROWS,64) dwords, PAIRED
    const float* __restrict__ psqt,           // (NROWS,8) fp32
    const unsigned short* __restrict__ ids16, // (B,64) u16: k<32 w, else b
    const float* __restrict__ us,
    const float* __restrict__ them,
    const int*   __restrict__ pcnt,
    unsigned short* __restrict__ Ag,          // (32,B,8) bf16, group-major slots
    float* __restrict__ psq_g,                // (B,)
    int B)
{
    __shared__ unsigned long long ldsT[20480];   // 163840 B = 160 KiB (gfx950 max)

    const int g    = blockIdx.x & 31;
    const int jb   = blockIdx.x >> 5;            // 0..7
    const int tid  = threadIdx.x;
    const int lane = tid & 63;
    const int wv   = tid >> 6;                   // wave 0..15
    const int SL   = B >> 3;                     // 2048 rows per slice

    // ---- psqt duty (VMEM; overlaps LDS fill + everyone's compute) ----
    {
        const int chunk = SL >> 5;               // 64 rows per block
        const int pw    = chunk >> 4;            // 4 rows per wave
        const int prow0 = jb * SL + g * chunk + wv * pw;
        for (int rr = 0; rr < pw; ++rr) {
            const int prow = prow0 + rr;         // wave-uniform
            const float usv = us[prow];
            int bucket = (pcnt[prow] - 1) >> 2;
            bucket = bucket > 7 ? 7 : bucket;
            const unsigned pidx = ids16[(size_t)prow * 64 + lane];
            float ps = psqt[(size_t)pidx * 8 + bucket];
            ps += __shfl_xor(ps, 16);
            ps += __shfl_xor(ps, 8);
            ps += __shfl_xor(ps, 4);
            ps += __shfl_xor(ps, 2);
            ps += __shfl_xor(ps, 1);
            const float pw_ = __shfl(ps, 0);
            const float pb_ = __shfl(ps, 32);
            if (lane == 0) psq_g[prow] = (pw_ - pb_) * (usv - 0.5f);
        }
    }

    // ---- LDS fill: plane g = 8 B/row strided from the row-major table ----
#pragma unroll
    for (int c = 0; c < 20; ++c) {
        const int r = c * 1024 + tid;            // 0..20479
        ldsT[r] = *(const unsigned long long*)(emb8 + (size_t)r * 64 + 2 * g);
    }
    __syncthreads();

    // ---- main: lane-per-row, 64 serial LDS refs per row ----
    const unsigned M = 0x00FF00FFu;
    const float c127 = 127.f / 128.f;
    const int passes = SL >> 10;                 // 2 for B=16384
    for (int p = 0; p < passes; ++p) {
        const int row = jb * SL + wv * (SL >> 4) + p * 64 + lane;
        const float usv = us[row];
        const float thv = them[row];
        const unsigned short* idr = ids16 + (size_t)row * 64;

        unsigned awlo0 = 0, awlo1 = 0, awhi0 = 0, awhi1 = 0;
        unsigned ablo0 = 0, ablo1 = 0, abhi0 = 0, abhi1 = 0;
#pragma unroll 8
        for (int k = 0; k < 32; k += 2) {
            const unsigned pr = *(const unsigned*)(idr + k);
            const unsigned i0 = pr & 0xffffu, i1 = pr >> 16;
            unsigned long long v0 = ldsT[i0 < 20480u ? i0 : 0u];
            unsigned long long v1 = ldsT[i1 < 20480u ? i1 : 0u];
            if (i0 == 20480u) v0 = 0x8080808080808080ULL;   // pad row
            if (i1 == 20480u) v1 = 0x8080808080808080ULL;
            const unsigned a0 = (unsigned)v0, a1 = (unsigned)(v0 >> 32);
            const unsigned b0 = (unsigned)v1, b1 = (unsigned)(v1 >> 32);
            awlo0 += a0 & M;  awhi0 += (a0 >> 8) & M;
            awlo1 += a1 & M;  awhi1 += (a1 >> 8) & M;
            awlo0 += b0 & M;  awhi0 += (b0 >> 8) & M;
            awlo1 += b1 & M;  awhi1 += (b1 >> 8) & M;
        }
#pragma unroll 8
        for (int k = 32; k < 64; k += 2) {
            const unsigned pr = *(const unsigned*)(idr + k);
            const unsigned i0 = pr & 0xffffu, i1 = pr >> 16;
            unsigned long long v0 = ldsT[i0 < 20480u ? i0 : 0u];
            unsigned long long v1 = ldsT[i1 < 20480u ? i1 : 0u];
            if (i0 == 20480u) v0 = 0x8080808080808080ULL;
            if (i1 == 20480u) v1 = 0x8080808080808080ULL;
            const unsigned a0 = (unsigned)v0, a1 = (unsigned)(v0 >> 32);
            const unsigned b0 = (unsigned)v1, b1 = (unsigned)(v1 >> 32);
            ablo0 += a0 & M;  abhi0 += (a0 >> 8) & M;
            ablo1 += a1 & M;  abhi1 += (a1 >> 8) & M;
            ablo0 += b0 & M;  abhi0 += (b0 >> 8) & M;
            ablo1 += b1 & M;  abhi1 += (b1 >> 8) & M;
        }

        // dequant + lane-local pair products (r6-verified math).
        // slot e (= 2d+h): P_e = product for feature 4g+e; Q_e for +128 side.
        float P[4], Q[4];
        const unsigned slo[2] = { awlo0, awlo1 }, shi[2] = { awhi0, awhi1 };
        const unsigned tlo[2] = { ablo0, ablo1 }, thi[2] = { abhi0, abhi1 };
#pragma unroll
        for (int d = 0; d < 2; ++d) {
#pragma unroll
            for (int h = 0; h < 2; ++h) {
                const int sh = h << 4;
                const float wA = ((int)((slo[d] >> sh) & 0xffffu) - 4096) * INVQS;
                const float wB = ((int)((shi[d] >> sh) & 0xffffu) - 4096) * INVQS;
                const float bA = ((int)((tlo[d] >> sh) & 0xffffu) - 4096) * INVQS;
                const float bB = ((int)((thi[d] >> sh) & 0xffffu) - 4096) * INVQS;
                const float PA = clamp01(usv * wA + thv * bA);
                const float PB = clamp01(usv * wB + thv * bB);
                const float QA = clamp01(usv * bA + thv * wA);
                const float QB = clamp01(usv * bB + thv * wB);
                P[2 * d + h] = PA * PB * c127;
                Q[2 * d + h] = QA * QB * c127;
            }
        }
        uint4 o;
        o.x = (unsigned)f2bf(P[0]) | ((unsigned)f2bf(P[1]) << 16);
        o.y = (unsigned)f2bf(P[2]) | ((unsigned)f2bf(P[3]) << 16);
        o.z = (unsigned)f2bf(Q[0]) | ((unsigned)f2bf(Q[1]) << 16);
        o.w = (unsigned)f2bf(Q[2]) | ((unsigned)f2bf(Q[3]) << 16);
        *(uint4*)(Ag + ((size_t)g * B + row) * 8) = o;   // coalesced: rows=lanes
    }
}

// ---------- phase 2+3: MFMA l1 + l2/l3 tail ----------
__global__ __launch_bounds__(512) void g_phase23(
    const unsigned short* __restrict__ Ag,    // (32,B,8) bf16 group-major
    const float* __restrict__ psq_g,          // (B,)
    const unsigned short* __restrict__ w1b,   // MFMA B frags, bf16 (permuted K)
    const float* __restrict__ b1c,            // folded (256,)
    const float* __restrict__ w2p,            // padded (256,64)
    const float* __restrict__ b2,
    const float* __restrict__ wo,
    const float* __restrict__ bo,
    const int*   __restrict__ pcnt,
    float* __restrict__ out,
    int B)
{
    __shared__ unsigned short A_lds[16 * 280];          // 8960 B (280: bank pad)
    __shared__ float l1c[8 * 16 * 36];                  // 18432 B
    __shared__ float psq_lds[16];
    __shared__ int   bkt_lds[16];

    const int tid  = threadIdx.x;
    const int lane = tid & 63;
    const int w    = tid >> 6;

    // cooperative copy Ag -> A_lds: thread = (group gg, row m); 16B each.
    {
        const int gg = tid >> 4, m = tid & 15;
        *(uint4*)&A_lds[m * 280 + gg * 8] =
            *(const uint4*)(Ag + ((size_t)gg * B + blockIdx.x * 16 + m) * 8);
    }
    if (tid < 16) {
        const int row = blockIdx.x * 16 + tid;
        int bucket = (pcnt[row] - 1) >> 2;
        bkt_lds[tid] = bucket > 7 ? 7 : bucket;
        psq_lds[tid] = psq_g[row];
    }
    __syncthreads();

    // ---------- phase 2: l1 via MFMA, wave w handles bucket w ----------
    {
        const int col = lane & 15;
        const int hi  = lane >> 4;
        const int bkt = w;
        f32x4 acc[2];
        acc[0] = (f32x4){0.f, 0.f, 0.f, 0.f};
        acc[1] = (f32x4){0.f, 0.f, 0.f, 0.f};

#pragma unroll
        for (int s = 0; s < 8; ++s) {
            const short8 a = *((const short8*)&A_lds[col * 280 + s * 32 + hi * 8]);
#pragma unroll
            for (int nt = 0; nt < 2; ++nt) {
                const short8 bf = *((const short8*)&w1b[(((bkt * 8 + s) * 2 + nt) * 64 + lane) * 8]);
                acc[nt] = __builtin_amdgcn_mfma_f32_16x16x32_bf16(a, bf, acc[nt], 0, 0, 0);
            }
        }
#pragma unroll
        for (int nt = 0; nt < 2; ++nt) {
            const float bias = b1c[bkt * 32 + nt * 16 + col];
#pragma unroll
            for (int reg = 0; reg < 4; ++reg) {
                const int mr = hi * 4 + reg;
                l1c[(bkt * 16 + mr) * 36 + nt * 16 + col] = acc[nt][reg] + bias;
            }
        }
    }
    __syncthreads();

    // ---------- phase 3: l2 + l3, thread = (row, output-pair), tid < 256 ----------
    if (tid < 256) {
        const int row = tid >> 4;
        const int jj  = tid & 15;
        const int bkt = bkt_lds[row];
        const float4* crow = (const float4*)&l1c[(bkt * 16 + row) * 36];
        float4 c4[8];
#pragma unroll
        for (int b5 = 0; b5 < 8; ++b5) c4[b5] = crow[b5];

        const float4* wr0 = (const float4*)&w2p[(bkt * 32 + jj) * 64];
        const float4* wr1 = (const float4*)&w2p[(bkt * 32 + jj + 16) * 64];
        float acc0 = 0.f, acc1 = 0.f;
        const float kq = 255.f / 256.f;
#pragma unroll
        for (int b5 = 0; b5 < 8; ++b5) {
            const float4 cv = c4[b5];
            float4 sq, ln;
            sq.x = clamp01(cv.x * cv.x * kq); ln.x = clamp01(cv.x);
            sq.y = clamp01(cv.y * cv.y * kq); ln.y = clamp01(cv.y);
            sq.z = clamp01(cv.z * cv.z * kq); ln.z = clamp01(cv.z);
            sq.w = clamp01(cv.w * cv.w * kq); ln.w = clamp01(cv.w);
            const float4 ws0 = wr0[b5], wl0 = wr0[8 + b5];
            const float4 ws1 = wr1[b5], wl1 = wr1[8 + b5];
            acc0 += sq.x * ws0.x + sq.y * ws0.y + sq.z * ws0.z + sq.w * ws0.w;
            acc0 += ln.x * wl0.x + ln.y * wl0.y + ln.z * wl0.z + ln.w * wl0.w;
            acc1 += sq.x * ws1.x + sq.y * ws1.y + sq.z * ws1.z + sq.w * ws1.w;
            acc1 += ln.x * wl1.x + ln.y * wl1.y + ln.z * wl1.z + ln.w * wl1.w;
        }
        const float t0 = clamp01(acc0 + b2[bkt * 32 + jj])      * wo[bkt * 32 + jj];
        const float t1 = clamp01(acc1 + b2[bkt * 32 + jj + 16]) * wo[bkt * 32 + jj + 16];
        float tsum = t0 + t1;
        tsum += __shfl_xor(tsum, 8);
        tsum += __shfl_xor(tsum, 4);
        tsum += __shfl_xor(tsum, 2);
        tsum += __shfl_xor(tsum, 1);
        if (jj == 0) {
            out[blockIdx.x * 16 + row] = tsum + bo[bkt] + c4[7].w + psq_lds[row];
        }
    }
}

// ---------- fp32 fallback (self-contained, no workspace) ----------
__global__ __launch_bounds__(256) void nnue_fwd_f32(
    const float* __restrict__ emb,
    const float* __restrict__ w1e, const float* __restrict__ fw1,
    const float* __restrict__ b1e, const float* __restrict__ fb1,
    const float* __restrict__ w2,  const float* __restrict__ b2,
    const float* __restrict__ wo,  const float* __restrict__ bo,
    const float* __restrict__ us,  const float* __restrict__ them,
    const int* __restrict__ w_idx, const int* __restrict__ b_idx,
    const int* __restrict__ pcnt,  float* __restrict__ out, int B)
{
    const int lane = threadIdx.x & 63;
    const int row  = blockIdx.x * 4 + (threadIdx.x >> 6);
    if (row >= B) return;
    const float usv = us[row];
    const float thv = them[row];
    int bucket = (pcnt[row] - 1) >> 2;
    bucket = bucket > 7 ? 7 : bucket;
    bucket = __builtin_amdgcn_readfirstlane(bucket);
    const int kk = lane & 31;
    const int myidx = (lane < 32) ? w_idx[row * 32 + kk] : b_idx[row * 32 + kk];
    float ps = emb[(size_t)myidx * EMBD + 256 + bucket];
    ps += __shfl_xor(ps, 16); ps += __shfl_xor(ps, 8);
    ps += __shfl_xor(ps, 4);  ps += __shfl_xor(ps, 2); ps += __shfl_xor(ps, 1);
    const float psq_w = __shfl(ps, 0);
    const float psq_b = __shfl(ps, 32);
    float4 aw = make_float4(0,0,0,0), ab = make_float4(0,0,0,0);
#pragma unroll
    for (int k = 0; k < 32; ++k) {
        const int iw = __shfl(myidx, k);
        const int ib = __shfl(myidx, 32 + k);
        const float4 vw = *((const float4*)(emb + (size_t)iw * EMBD) + lane);
        const float4 vb = *((const float4*)(emb + (size_t)ib * EMBD) + lane);
        aw.x += vw.x; aw.y += vw.y; aw.z += vw.z; aw.w += vw.w;
        ab.x += vb.x; ab.y += vb.y; ab.z += vb.z; ab.w += vb.w;
    }
    float4 p, q;
    p.x = clamp01(usv*aw.x + thv*ab.x); p.y = clamp01(usv*aw.y + thv*ab.y);
    p.z = clamp01(usv*aw.z + thv*ab.z); p.w = clamp01(usv*aw.w + thv*ab.w);
    q.x = clamp01(usv*ab.x + thv*aw.x); q.y = clamp01(usv*ab.y + thv*aw.y);
    q.z = clamp01(usv*ab.z + thv*aw.z); q.w = clamp01(usv*ab.w + thv*aw.w);
    float4 po, qo;
    po.x = __shfl_xor(p.x,32); po.y = __shfl_xor(p.y,32);
    po.z = __shfl_xor(p.z,32); po.w = __shfl_xor(p.w,32);
    qo.x = __shfl_xor(q.x,32); qo.y = __shfl_xor(q.y,32);
    qo.z = __shfl_xor(q.z,32); qo.w = __shfl_xor(q.w,32);
    const float c127 = 127.f/128.f;
    float4 l0f;
    if (lane < 32) { l0f.x=p.x*po.x*c127; l0f.y=p.y*po.y*c127; l0f.z=p.z*po.z*c127; l0f.w=p.w*po.w*c127; }
    else           { l0f.x=q.x*qo.x*c127; l0f.y=q.y*qo.y*c127; l0f.z=q.z*qo.z*c127; l0f.w=q.w*qo.w*c127; }
    float part[32];
    const float4* w1p = (const float4*)(w1e + (size_t)bucket * 8192);
    const float4* f1p = (const float4*)fw1;
#pragma unroll
    for (int j = 0; j < 32; ++j) {
        float4 wv = w1p[j*64 + lane];
        float4 fv = f1p[j*64 + lane];
        wv.x+=fv.x; wv.y+=fv.y; wv.z+=fv.z; wv.w+=fv.w;
        part[j] = l0f.x*wv.x + l0f.y*wv.y + l0f.z*wv.z + l0f.w*wv.w;
    }
#pragma unroll
    for (int j = 0; j < 32; ++j) {
        float v = part[j];
        v += __shfl_xor(v,32); v += __shfl_xor(v,16); v += __shfl_xor(v,8);
        v += __shfl_xor(v,4);  v += __shfl_xor(v,2);  v += __shfl_xor(v,1);
        part[j] = v + b1e[bucket*32 + j] + fb1[j];
    }
    const float l1x_out = part[31];
    float acc2 = 0.f;
    if (lane < 32) {
        const float* w2r = w2 + (size_t)(bucket*32 + lane) * 62;
#pragma unroll
        for (int i = 0; i < 31; ++i) {
            const float a = part[i];
            acc2 += clamp01(a*a*(255.f/256.f)) * w2r[i];
            acc2 += clamp01(a) * w2r[31+i];
        }
        acc2 += b2[bucket*32 + lane];
        acc2 = clamp01(acc2) * wo[bucket*32 + lane];
    }
    acc2 += __shfl_xor(acc2,16); acc2 += __shfl_xor(acc2,8);
    acc2 += __shfl_xor(acc2,4);  acc2 += __shfl_xor(acc2,2); acc2 += __shfl_xor(acc2,1);
    if (lane == 0)
        out[row] = acc2 + bo[bucket] + l1x_out + (psq_w - psq_b) * (usv - 0.5f);
}

extern "C" void kernel_launch(void* const* d_in, const int* in_sizes, int n_in,
                              void* d_out, int out_size, void* d_ws, size_t ws_size,
                              hipStream_t stream) {
    const float* emb  = (const float*)d_in[0];
    const float* w1   = (const float*)d_in[1];
    const float* b1   = (const float*)d_in[2];
    const float* fw1  = (const float*)d_in[3];
    const float* fb1  = (const float*)d_in[4];
    const float* w2   = (const float*)d_in[5];
    const float* b2   = (const float*)d_in[6];
    const float* wo   = (const float*)d_in[7];
    const float* bo   = (const float*)d_in[8];
    const float* us   = (const float*)d_in[9];
    const float* them = (const float*)d_in[10];
    const int*   wi   = (const int*)d_in[11];
    const int*   bi   = (const int*)d_in[12];
    const int*   pc   = (const int*)d_in[13];
    float* out = (float*)d_out;

    const int B = in_sizes[9];               // 16384

    const size_t emb8_bytes = (size_t)NROWS * 256;   // 5,243,136
    const size_t psqt_bytes = (size_t)NROWS * 8 * 4; //   655,392
    const size_t w1b_bytes  = 65536 * 2;
    const size_t b1c_bytes  = 256 * 4;
    const size_t w2p_bytes  = 16384 * 4;
    const size_t Ag_bytes   = (size_t)B * 256 * 2;   // 8,388,608 (32 planes x B x 16B)
    const size_t psq_bytes  = (size_t)B * 4;
    const size_t ids_bytes  = (size_t)B * 64 * 2;    // 2,097,152
    const size_t need = emb8_bytes + psqt_bytes + w1b_bytes + b1c_bytes +
                        w2p_bytes + Ag_bytes + psq_bytes + ids_bytes;

    if (ws_size >= need && B == 16384) {
        char* p = (char*)d_ws;
        unsigned int*   emb8 = (unsigned int*)p;     p += emb8_bytes;
        float*          psqt = (float*)p;            p += psqt_bytes;
        unsigned short* w1b  = (unsigned short*)p;   p += w1b_bytes;
        float*          b1c  = (float*)p;            p += b1c_bytes;
        float*          w2p  = (float*)p;            p += w2p_bytes;
        unsigned short* Ag   = (unsigned short*)p;   p += Ag_bytes;
        float*          psq  = (float*)p;            p += psq_bytes;
        unsigned*       ids  = (unsigned*)p;

        prep_all<<<NR4 + 256 + 512, 256, 0, stream>>>(emb, emb8, psqt,
                                                      w1, fw1, b1, fb1, w2,
                                                      wi, bi, w1b, b1c, w2p, ids);
        g_phase1L<<<256, 1024, 0, stream>>>(emb8, psqt, (const unsigned short*)ids,
                                            us, them, pc, Ag, psq, B);
        g_phase23<<<B / 16, 512, 0, stream>>>(Ag, psq, w1b, b1c, w2p,
                                              b2, wo, bo, pc, out, B);
    } else {
        nnue_fwd_f32<<<(B + 3) / 4, 256, 0, stream>>>(emb, w1, fw1, b1, fb1,
                                                      w2, b2, wo, bo, us, them, wi, bi, pc, out, B);
    }
}

// Round 8
// 135.823 us; speedup vs baseline: 1.2560x; 1.2560x over previous
//
#include <hip/hip_runtime.h>

// ROOFLINE NOTE (r8): phase-1 gather is bound by cache-line REQUEST RATE, not
// BW/latency/occupancy. 3 line-requests per feature ref (2 emb + 1 psqt) x
// 1.05M refs = 3.15M requests / (~27 lines/cyc chip-wide) = ~48.6us; seven
// structurally different implementations (r0-r7: forced-MLP, quad-gather,
// split high-TLP, L2 column tiles, paired layout, LDS-resident table) all
// measured 45-50us. This file = the best-measured variant (r3, 46.8us kernel,
// 137.7us total).

#define EMBD 264        // L1(256) + 8 psqt
#define NROWS 20481     // HALFKP+1
#define NR4   5121      // ceil(NROWS/4)
#define QS 5080.0f      // int8 scale: 127/0.025
#define INVQS (1.0f/5080.0f)

typedef short short8 __attribute__((ext_vector_type(8)));
typedef float f32x4  __attribute__((ext_vector_type(4)));

__device__ __forceinline__ float clamp01(float x) { return fminf(fmaxf(x, 0.f), 1.f); }
__device__ __forceinline__ unsigned short f2bf(float f) {
    unsigned u = __float_as_uint(f);
    u += 0x7fffu + ((u >> 16) & 1u);   // RNE
    return (unsigned short)(u >> 16);
}

// Merged prep: blocks [0, NR4) quantize emb -> emb8/psqt; blocks [NR4, NR4+256)
// build w1b (folded bf16 MFMA B-frags), b1c, w2p.
__global__ void prep_all(const float* __restrict__ emb, unsigned int* __restrict__ emb8,
                         float* __restrict__ psqt,
                         const float* __restrict__ w1, const float* __restrict__ fw1,
                         const float* __restrict__ b1, const float* __restrict__ fb1,
                         const float* __restrict__ w2,
                         unsigned short* __restrict__ w1b, float* __restrict__ b1c,
                         float* __restrict__ w2p) {
    if (blockIdx.x < NR4) {
        const int r = blockIdx.x * 4 + (threadIdx.x >> 6);
        const int t = threadIdx.x & 63;
        if (r >= NROWS) return;
        const bool pad = (r == NROWS - 1);
        const float4 v = *((const float4*)(emb + (size_t)r * EMBD) + t);
        int q0 = pad ? 128 : (int)rintf(v.x * QS) + 128;
        int q1 = pad ? 128 : (int)rintf(v.y * QS) + 128;
        int q2 = pad ? 128 : (int)rintf(v.z * QS) + 128;
        int q3 = pad ? 128 : (int)rintf(v.w * QS) + 128;
        q0 = min(max(q0, 0), 255); q1 = min(max(q1, 0), 255);
        q2 = min(max(q2, 0), 255); q3 = min(max(q3, 0), 255);
        emb8[(size_t)r * 64 + t] = (unsigned)q0 | ((unsigned)q1 << 8) |
                                   ((unsigned)q2 << 16) | ((unsigned)q3 << 24);
        if (t < 8) {
            float pv = emb[(size_t)r * EMBD + 256 + t];
            psqt[r * 8 + t] = pad ? 0.f : pv;
        }
    } else {
        const int e = (blockIdx.x - NR4) * 256 + threadIdx.x;   // 0..65535
        const int bkt = e >> 13, rem = e & 8191;
        const int s = rem >> 10, rem2 = rem & 1023;
        const int nt = rem2 >> 9, rem3 = rem2 & 511;
        const int ln = rem3 >> 3, j = rem3 & 7;
        const int n  = nt * 16 + (ln & 15);
        const int hi = ln >> 4;
        const int k  = s * 32 + hi * 8 + j;
        const float v = w1[(bkt * 32 + n) * 256 + k] + fw1[n * 256 + k];
        w1b[e] = f2bf(v);
        if (e < 256) b1c[e] = b1[e] + fb1[e & 31];
        if (e < 16384) {
            const int jr = e >> 6, i = e & 63;
            float x = 0.f;
            if (i < 31) x = w2[jr * 62 + i];
            else if (i >= 32 && i < 63) x = w2[jr * 62 + i - 1];
            w2p[e] = x;
        }
    }
}

__global__ __launch_bounds__(512, 4) void nnue_fwd_mfma(
    const unsigned int* __restrict__ emb8,    // (NROWS,64) dwords, biased u8
    const float* __restrict__ psqt,           // (NROWS,8) fp32
    const unsigned short* __restrict__ w1b,   // MFMA B frags, bf16
    const float* __restrict__ b1c,            // folded (256,)
    const float* __restrict__ w2p,            // padded (256,64)
    const float* __restrict__ b2,
    const float* __restrict__ wo,
    const float* __restrict__ bo,
    const float* __restrict__ us,
    const float* __restrict__ them,
    const int*   __restrict__ w_idx,
    const int*   __restrict__ b_idx,
    const int*   __restrict__ pcnt,
    float* __restrict__ out,
    int B)
{
    // 512 threads = 8 waves; 16 batch rows per block, 2 rows per wave.
    __shared__ unsigned short A_lds[16 * 280];          // 8960 B
    __shared__ float l1c[8 * 16 * 36];                  // 18432 B
    __shared__ float psq_lds[16];
    __shared__ int   bkt_lds[16];

    const int tid  = threadIdx.x;
    const int lane = tid & 63;
    const int w    = tid >> 6;            // wave 0..7

    // ---------- phase 1: gather (2 rows per wave) ----------
    // Wide-gather: one global_load_dwordx4 fetches FOUR different feature rows
    // (4 groups of 16 lanes; 16 lanes x 16B = one 256B row). Line-request
    // count (the binding constraint) is unchanged, but VMEM instruction count
    // is 3.6x lower than dword gathers -- best measured variant (46.8us).
    const int t = lane & 15;              // position within a row (16B chunks)
    const int g = lane >> 4;              // group 0..3 (which row of a quad)
    const int d = (t << 2) + g;           // dword of the row this lane OWNS

    for (int rr = 0; rr < 2; ++rr) {
        const int m = w * 2 + rr;
        const int grow = __builtin_amdgcn_readfirstlane(blockIdx.x * 16 + m); // B%16==0

        const float usv = us[grow];
        const float thv = them[grow];
        int bucket = (pcnt[grow] - 1) >> 2;
        bucket = bucket > 7 ? 7 : bucket;
        bucket = __builtin_amdgcn_readfirstlane(bucket);

        const int* wrow = w_idx + grow * 32;
        const int* brow = b_idx + grow * 32;

        // One coalesced load: lanes 0..31 hold w indices, 32..63 hold b.
        const int kk = lane & 31;
        const int iv = (lane < 32) ? wrow[kk] : brow[kk];

        // psqt: per-lane scattered gather, issued early so its latency hides
        // under the bulk row gathers.
        float ps = psqt[(size_t)iv * 8 + bucket];

        // 16 quad-row gathers (8 w-side + 8 b-side).
        uint4 vws[8], vbs[8];
#pragma unroll
        for (int k = 0; k < 8; ++k) {
            const int rw = __shfl(iv, (k << 2) + g);
            vws[k] = *(const uint4*)((const char*)emb8 +
                                     (((unsigned)rw << 8) + (unsigned)(t << 4)));
        }
#pragma unroll
        for (int k = 0; k < 8; ++k) {
            const int rb = __shfl(iv, 32 + (k << 2) + g);
            vbs[k] = *(const uint4*)((const char*)emb8 +
                                     (((unsigned)rb << 8) + (unsigned)(t << 4)));
        }

        // Packed u16 accumulate, group-local (8 rows per group per side).
        const unsigned M = 0x00FF00FFu;
        unsigned a0w[4] = {0,0,0,0}, a1w[4] = {0,0,0,0};
        unsigned a0b[4] = {0,0,0,0}, a1b[4] = {0,0,0,0};
#pragma unroll
        for (int k = 0; k < 8; ++k) {
            a0w[0] += vws[k].x & M;  a1w[0] += (vws[k].x >> 8) & M;
            a0w[1] += vws[k].y & M;  a1w[1] += (vws[k].y >> 8) & M;
            a0w[2] += vws[k].z & M;  a1w[2] += (vws[k].z >> 8) & M;
            a0w[3] += vws[k].w & M;  a1w[3] += (vws[k].w >> 8) & M;
        }
#pragma unroll
        for (int k = 0; k < 8; ++k) {
            a0b[0] += vbs[k].x & M;  a1b[0] += (vbs[k].x >> 8) & M;
            a0b[1] += vbs[k].y & M;  a1b[1] += (vbs[k].y >> 8) & M;
            a0b[2] += vbs[k].z & M;  a1b[2] += (vbs[k].z >> 8) & M;
            a0b[3] += vbs[k].w & M;  a1b[3] += (vbs[k].w >> 8) & M;
        }

        // Cross-group reduce: sum the 4 groups (lanes t, t+16, t+32, t+48).
        // Max per u16 half: 32 rows * 255 = 8160 < 65536, no overflow.
#pragma unroll
        for (int j = 0; j < 4; ++j) {
            a0w[j] += __shfl_xor(a0w[j], 16);  a0w[j] += __shfl_xor(a0w[j], 32);
            a1w[j] += __shfl_xor(a1w[j], 16);  a1w[j] += __shfl_xor(a1w[j], 32);
            a0b[j] += __shfl_xor(a0b[j], 16);  a0b[j] += __shfl_xor(a0b[j], 32);
            a1b[j] += __shfl_xor(a1b[j], 16);  a1b[j] += __shfl_xor(a1b[j], 32);
        }
        // Each lane now owns dword d = 4t+g: select slot j = g.
        const bool gl = (g & 1) != 0, gh = (g & 2) != 0;
        const unsigned aw0 = gh ? (gl ? a0w[3] : a0w[2]) : (gl ? a0w[1] : a0w[0]);
        const unsigned aw1 = gh ? (gl ? a1w[3] : a1w[2]) : (gl ? a1w[1] : a1w[0]);
        const unsigned ab0 = gh ? (gl ? a0b[3] : a0b[2]) : (gl ? a0b[1] : a0b[0]);
        const unsigned ab1 = gh ? (gl ? a1b[3] : a1b[2]) : (gl ? a1b[1] : a1b[0]);

        // psqt reduce
        ps += __shfl_xor(ps, 16);
        ps += __shfl_xor(ps, 8);
        ps += __shfl_xor(ps, 4);
        ps += __shfl_xor(ps, 2);
        ps += __shfl_xor(ps, 1);
        const float psq_w = __shfl(ps, 0);
        const float psq_b = __shfl(ps, 32);

        // Lane's dword d packs features 4d..4d+3: (x,y,z,w) = (b0lo,b1lo,b0hi,b1hi)
        float4 aw4, ab4;
        aw4.x = ((int)(aw0 & 0xffffu) - 4096) * INVQS;
        aw4.y = ((int)(aw1 & 0xffffu) - 4096) * INVQS;
        aw4.z = ((int)(aw0 >> 16)     - 4096) * INVQS;
        aw4.w = ((int)(aw1 >> 16)     - 4096) * INVQS;
        ab4.x = ((int)(ab0 & 0xffffu) - 4096) * INVQS;
        ab4.y = ((int)(ab1 & 0xffffu) - 4096) * INVQS;
        ab4.z = ((int)(ab0 >> 16)     - 4096) * INVQS;
        ab4.w = ((int)(ab1 >> 16)     - 4096) * INVQS;

        float4 p, q;
        p.x = clamp01(usv * aw4.x + thv * ab4.x);
        p.y = clamp01(usv * aw4.y + thv * ab4.y);
        p.z = clamp01(usv * aw4.z + thv * ab4.z);
        p.w = clamp01(usv * aw4.w + thv * ab4.w);
        q.x = clamp01(usv * ab4.x + thv * aw4.x);
        q.y = clamp01(usv * ab4.y + thv * aw4.y);
        q.z = clamp01(usv * ab4.z + thv * aw4.z);
        q.w = clamp01(usv * ab4.w + thv * aw4.w);

        // Pairing: feature f partners f+128 = dword d+32 = lane xor 8.
        float4 po, qo;
        po.x = __shfl_xor(p.x, 8); po.y = __shfl_xor(p.y, 8);
        po.z = __shfl_xor(p.z, 8); po.w = __shfl_xor(p.w, 8);
        qo.x = __shfl_xor(q.x, 8); qo.y = __shfl_xor(q.y, 8);
        qo.z = __shfl_xor(q.z, 8); qo.w = __shfl_xor(q.w, 8);
        const float c127 = 127.f / 128.f;
        float4 l0f;
        if (t < 8) {   // d < 32: w-half products (A entries 4d..4d+3 in [0,128))
            l0f.x = p.x * po.x * c127; l0f.y = p.y * po.y * c127;
            l0f.z = p.z * po.z * c127; l0f.w = p.w * po.w * c127;
        } else {       // d >= 32: b-half products (entries in [128,256))
            l0f.x = q.x * qo.x * c127; l0f.y = q.y * qo.y * c127;
            l0f.z = q.z * qo.z * c127; l0f.w = q.w * qo.w * c127;
        }

        const unsigned lo  = (unsigned)f2bf(l0f.x) | ((unsigned)f2bf(l0f.y) << 16);
        const unsigned hi2 = (unsigned)f2bf(l0f.z) | ((unsigned)f2bf(l0f.w) << 16);
        *((unsigned long long*)&A_lds[m * 280 + d * 4]) =
            ((unsigned long long)hi2 << 32) | (unsigned long long)lo;
        if (lane == 0) {
            psq_lds[m] = (psq_w - psq_b) * (usv - 0.5f);
            bkt_lds[m] = bucket;
        }
    }
    __syncthreads();

    // ---------- phase 2: l1 via MFMA, wave w handles bucket w ----------
    {
        const int col = lane & 15;
        const int hi  = lane >> 4;
        const int bkt = w;
        f32x4 acc[2];
        acc[0] = (f32x4){0.f, 0.f, 0.f, 0.f};
        acc[1] = (f32x4){0.f, 0.f, 0.f, 0.f};

#pragma unroll
        for (int s = 0; s < 8; ++s) {
            const short8 a = *((const short8*)&A_lds[col * 280 + s * 32 + hi * 8]);
#pragma unroll
            for (int nt = 0; nt < 2; ++nt) {
                const short8 bf = *((const short8*)&w1b[(((bkt * 8 + s) * 2 + nt) * 64 + lane) * 8]);
                acc[nt] = __builtin_amdgcn_mfma_f32_16x16x32_bf16(a, bf, acc[nt], 0, 0, 0);
            }
        }
#pragma unroll
        for (int nt = 0; nt < 2; ++nt) {
            const float bias = b1c[bkt * 32 + nt * 16 + col];
#pragma unroll
            for (int reg = 0; reg < 4; ++reg) {
                const int mr = hi * 4 + reg;
                l1c[(bkt * 16 + mr) * 36 + nt * 16 + col] = acc[nt][reg] + bias;
            }
        }
    }
    __syncthreads();

    // ---------- phase 3: l2 + l3, thread = (row, output-pair), tid < 256 ----------
    if (tid < 256) {
        const int row = tid >> 4;
        const int jj  = tid & 15;
        const int bkt = bkt_lds[row];
        const float4* crow = (const float4*)&l1c[(bkt * 16 + row) * 36];
        float4 c4[8];
#pragma unroll
        for (int b5 = 0; b5 < 8; ++b5) c4[b5] = crow[b5];

        const float4* wr0 = (const float4*)&w2p[(bkt * 32 + jj) * 64];
        const float4* wr1 = (const float4*)&w2p[(bkt * 32 + jj + 16) * 64];
        float acc0 = 0.f, acc1 = 0.f;
        const float kq = 255.f / 256.f;
#pragma unroll
        for (int b5 = 0; b5 < 8; ++b5) {
            const float4 cv = c4[b5];
            float4 sq, ln;
            sq.x = clamp01(cv.x * cv.x * kq); ln.x = clamp01(cv.x);
            sq.y = clamp01(cv.y * cv.y * kq); ln.y = clamp01(cv.y);
            sq.z = clamp01(cv.z * cv.z * kq); ln.z = clamp01(cv.z);
            sq.w = clamp01(cv.w * cv.w * kq); ln.w = clamp01(cv.w);
            const float4 ws0 = wr0[b5], wl0 = wr0[8 + b5];
            const float4 ws1 = wr1[b5], wl1 = wr1[8 + b5];
            acc0 += sq.x * ws0.x + sq.y * ws0.y + sq.z * ws0.z + sq.w * ws0.w;
            acc0 += ln.x * wl0.x + ln.y * wl0.y + ln.z * wl0.z + ln.w * wl0.w;
            acc1 += sq.x * ws1.x + sq.y * ws1.y + sq.z * ws1.z + sq.w * ws1.w;
            acc1 += ln.x * wl1.x + ln.y * wl1.y + ln.z * wl1.z + ln.w * wl1.w;
        }
        const float t0 = clamp01(acc0 + b2[bkt * 32 + jj])      * wo[bkt * 32 + jj];
        const float t1 = clamp01(acc1 + b2[bkt * 32 + jj + 16]) * wo[bkt * 32 + jj + 16];
        float tsum = t0 + t1;
        tsum += __shfl_xor(tsum, 8);
        tsum += __shfl_xor(tsum, 4);
        tsum += __shfl_xor(tsum, 2);
        tsum += __shfl_xor(tsum, 1);
        if (jj == 0) {
            out[blockIdx.x * 16 + row] = tsum + bo[bkt] + c4[7].w + psq_lds[row];
        }
    }
}

// ---------- fp32 fallback (self-contained, no workspace) ----------
__global__ __launch_bounds__(256) void nnue_fwd_f32(
    const float* __restrict__ emb,
    const float* __restrict__ w1e, const float* __restrict__ fw1,
    const float* __restrict__ b1e, const float* __restrict__ fb1,
    const float* __restrict__ w2,  const float* __restrict__ b2,
    const float* __restrict__ wo,  const float* __restrict__ bo,
    const float* __restrict__ us,  const float* __restrict__ them,
    const int* __restrict__ w_idx, const int* __restrict__ b_idx,
    const int* __restrict__ pcnt,  float* __restrict__ out, int B)
{
    const int lane = threadIdx.x & 63;
    const int row  = blockIdx.x * 4 + (threadIdx.x >> 6);
    if (row >= B) return;
    const float usv = us[row];
    const float thv = them[row];
    int bucket = (pcnt[row] - 1) >> 2;
    bucket = bucket > 7 ? 7 : bucket;
    bucket = __builtin_amdgcn_readfirstlane(bucket);
    const int kk = lane & 31;
    const int myidx = (lane < 32) ? w_idx[row * 32 + kk] : b_idx[row * 32 + kk];
    float ps = emb[(size_t)myidx * EMBD + 256 + bucket];
    ps += __shfl_xor(ps, 16); ps += __shfl_xor(ps, 8);
    ps += __shfl_xor(ps, 4);  ps += __shfl_xor(ps, 2); ps += __shfl_xor(ps, 1);
    const float psq_w = __shfl(ps, 0);
    const float psq_b = __shfl(ps, 32);
    float4 aw = make_float4(0,0,0,0), ab = make_float4(0,0,0,0);
#pragma unroll
    for (int k = 0; k < 32; ++k) {
        const int iw = __shfl(myidx, k);
        const int ib = __shfl(myidx, 32 + k);
        const float4 vw = *((const float4*)(emb + (size_t)iw * EMBD) + lane);
        const float4 vb = *((const float4*)(emb + (size_t)ib * EMBD) + lane);
        aw.x += vw.x; aw.y += vw.y; aw.z += vw.z; aw.w += vw.w;
        ab.x += vb.x; ab.y += vb.y; ab.z += vb.z; ab.w += vb.w;
    }
    float4 p, q;
    p.x = clamp01(usv*aw.x + thv*ab.x); p.y = clamp01(usv*aw.y + thv*ab.y);
    p.z = clamp01(usv*aw.z + thv*ab.z); p.w = clamp01(usv*aw.w + thv*ab.w);
    q.x = clamp01(usv*ab.x + thv*aw.x); q.y = clamp01(usv*ab.y + thv*aw.y);
    q.z = clamp01(usv*ab.z + thv*aw.z); q.w = clamp01(usv*ab.w + thv*aw.w);
    float4 po, qo;
    po.x = __shfl_xor(p.x,32); po.y = __shfl_xor(p.y,32);
    po.z = __shfl_xor(p.z,32); po.w = __shfl_xor(p.w,32);
    qo.x = __shfl_xor(q.x,32); qo.y = __shfl_xor(q.y,32);
    qo.z = __shfl_xor(q.z,32); qo.w = __shfl_xor(q.w,32);
    const float c127 = 127.f/128.f;
    float4 l0f;
    if (lane < 32) { l0f.x=p.x*po.x*c127; l0f.y=p.y*po.y*c127; l0f.z=p.z*po.z*c127; l0f.w=p.w*po.w*c127; }
    else           { l0f.x=q.x*qo.x*c127; l0f.y=q.y*qo.y*c127; l0f.z=q.z*qo.z*c127; l0f.w=q.w*qo.w*c127; }
    float part[32];
    const float4* w1p = (const float4*)(w1e + (size_t)bucket * 8192);
    const float4* f1p = (const float4*)fw1;
#pragma unroll
    for (int j = 0; j < 32; ++j) {
        float4 wv = w1p[j*64 + lane];
        float4 fv = f1p[j*64 + lane];
        wv.x+=fv.x; wv.y+=fv.y; wv.z+=fv.z; wv.w+=fv.w;
        part[j] = l0f.x*wv.x + l0f.y*wv.y + l0f.z*wv.z + l0f.w*wv.w;
    }
#pragma unroll
    for (int j = 0; j < 32; ++j) {
        float v = part[j];
        v += __shfl_xor(v,32); v += __shfl_xor(v,16); v += __shfl_xor(v,8);
        v += __shfl_xor(v,4);  v += __shfl_xor(v,2);  v += __shfl_xor(v,1);
        part[j] = v + b1e[bucket*32 + j] + fb1[j];
    }
    const float l1x_out = part[31];
    float acc2 = 0.f;
    if (lane < 32) {
        const float* w2r = w2 + (size_t)(bucket*32 + lane) * 62;
#pragma unroll
        for (int i = 0; i < 31; ++i) {
            const float a = part[i];
            acc2 += clamp01(a*a*(255.f/256.f)) * w2r[i];
            acc2 += clamp01(a) * w2r[31+i];
        }
        acc2 += b2[bucket*32 + lane];
        acc2 = clamp01(acc2) * wo[bucket*32 + lane];
    }
    acc2 += __shfl_xor(acc2,16); acc2 += __shfl_xor(acc2,8);
    acc2 += __shfl_xor(acc2,4);  acc2 += __shfl_xor(acc2,2); acc2 += __shfl_xor(acc2,1);
    if (lane == 0)
        out[row] = acc2 + bo[bucket] + l1x_out + (psq_w - psq_b) * (usv - 0.5f);
}

extern "C" void kernel_launch(void* const* d_in, const int* in_sizes, int n_in,
                              void* d_out, int out_size, void* d_ws, size_t ws_size,
                              hipStream_t stream) {
    const float* emb  = (const float*)d_in[0];
    const float* w1   = (const float*)d_in[1];
    const float* b1   = (const float*)d_in[2];
    const float* fw1  = (const float*)d_in[3];
    const float* fb1  = (const float*)d_in[4];
    const float* w2   = (const float*)d_in[5];
    const float* b2   = (const float*)d_in[6];
    const float* wo   = (const float*)d_in[7];
    const float* bo   = (const float*)d_in[8];
    const float* us   = (const float*)d_in[9];
    const float* them = (const float*)d_in[10];
    const int*   wi   = (const int*)d_in[11];
    const int*   bi   = (const int*)d_in[12];
    const int*   pc   = (const int*)d_in[13];
    float* out = (float*)d_out;

    const int B = in_sizes[9];               // 16384

    const size_t emb8_bytes = (size_t)NROWS * 256;   // 5,243,136
    const size_t psqt_bytes = (size_t)NROWS * 8 * 4; //   655,392
    const size_t w1b_bytes  = 65536 * 2;
    const size_t b1c_bytes  = 256 * 4;
    const size_t w2p_bytes  = 16384 * 4;
    const size_t need = emb8_bytes + psqt_bytes + w1b_bytes + b1c_bytes + w2p_bytes;

    if (ws_size >= need && (B % 16) == 0) {
        char* p = (char*)d_ws;
        unsigned int*   emb8 = (unsigned int*)p;     p += emb8_bytes;
        float*          psqt = (float*)p;            p += psqt_bytes;
        unsigned short* w1b  = (unsigned short*)p;   p += w1b_bytes;
        float*          b1c  = (float*)p;            p += b1c_bytes;
        float*          w2p  = (float*)p;

        prep_all<<<NR4 + 256, 256, 0, stream>>>(emb, emb8, psqt,
                                                w1, fw1, b1, fb1, w2, w1b, b1c, w2p);
        nnue_fwd_mfma<<<B / 16, 512, 0, stream>>>(emb8, psqt, w1b, b1c, w2p,
                                                  b2, wo, bo, us, them, wi, bi, pc, out, B);
    } else {
        nnue_fwd_f32<<<(B + 3) / 4, 256, 0, stream>>>(emb, w1, fw1, b1, fb1,
                                                      w2, b2, wo, bo, us, them, wi, bi, pc, out, B);
    }
}